// Round 1
// baseline (257.143 us; speedup 1.0000x reference)
//
#include <hip/hip_runtime.h>
#include <stdint.h>

#define M_DIM 8192
#define N_DIM 4096
#define K_DIM 4096
#define QMAXF 127.0f
#define QDIVF 127.5f

typedef int v4i __attribute__((ext_vector_type(4)));

// ---------------- address-space helpers for global_load_lds ----------------
typedef __attribute__((address_space(3))) void lds_void_t;
typedef __attribute__((address_space(1))) const void glb_void_t;

static __device__ __forceinline__ void load_lds16(const void* g, void* l) {
    __builtin_amdgcn_global_load_lds((glb_void_t*)g, (lds_void_t*)l, 16, 0, 0);
}

// ---------------- kernel 1: per-row absmax -> scale (lhs) ----------------
__global__ __launch_bounds__(256) void row_scale_kernel(
        const float* __restrict__ lhs, float* __restrict__ sL) {
    const int row = blockIdx.x;
    const float4* rp = (const float4*)(lhs + (size_t)row * K_DIM);
    const int t = threadIdx.x;
    float m = 0.0f;
#pragma unroll
    for (int i = 0; i < 4; ++i) {
        float4 v = rp[t + i * 256];
        m = fmaxf(m, fmaxf(fmaxf(fabsf(v.x), fabsf(v.y)),
                           fmaxf(fabsf(v.z), fabsf(v.w))));
    }
#pragma unroll
    for (int off = 32; off; off >>= 1) m = fmaxf(m, __shfl_down(m, off, 64));
    __shared__ float wmax[4];
    if ((t & 63) == 0) wmax[t >> 6] = m;
    __syncthreads();
    if (t == 0) {
        float mm = fmaxf(fmaxf(wmax[0], wmax[1]), fmaxf(wmax[2], wmax[3]));
        float s = mm / QDIVF;
        sL[row] = (s == 0.0f) ? 1.0f : s;
    }
}

// ---------------- kernel 2a: per-col absmax partial (rhs) ----------------
__global__ __launch_bounds__(256) void col_absmax_kernel(
        const float* __restrict__ rhs, unsigned* __restrict__ bits) {
    const int col = blockIdx.x * 256 + threadIdx.x;
    const int r0 = blockIdx.y * 64;
    float m = 0.0f;
#pragma unroll 4
    for (int r = 0; r < 64; ++r)
        m = fmaxf(m, fabsf(rhs[(size_t)(r0 + r) * N_DIM + col]));
    atomicMax(&bits[col], __float_as_uint(m));   // abs values >= 0: bit order == float order
}

// ---------------- kernel 2b: bits -> scale ----------------
__global__ __launch_bounds__(256) void col_scale_kernel(
        const unsigned* __restrict__ bits, float* __restrict__ sR) {
    const int c = blockIdx.x * 256 + threadIdx.x;
    float s = __uint_as_float(bits[c]) / QDIVF;
    sR[c] = (s == 0.0f) ? 1.0f : s;
}

// ---------------- kernel 3: quantize lhs (row-major int8) ----------------
__global__ __launch_bounds__(256) void quant_lhs_kernel(
        const float* __restrict__ lhs, const float* __restrict__ sL,
        int8_t* __restrict__ ql) {
    const size_t idx = (size_t)blockIdx.x * 256 + threadIdx.x; // float4 index
    const int row = (int)(idx >> 10);                          // 1024 float4 per row
    const float s = sL[row];
    float4 v = ((const float4*)lhs)[idx];
    int q0 = (int)fminf(fmaxf(rintf(v.x / s), -QMAXF), QMAXF);
    int q1 = (int)fminf(fmaxf(rintf(v.y / s), -QMAXF), QMAXF);
    int q2 = (int)fminf(fmaxf(rintf(v.z / s), -QMAXF), QMAXF);
    int q3 = (int)fminf(fmaxf(rintf(v.w / s), -QMAXF), QMAXF);
    unsigned packed = (q0 & 255) | ((q1 & 255) << 8) | ((q2 & 255) << 16)
                    | ((unsigned)(q3 & 255) << 24);
    ((unsigned*)ql)[idx] = packed;
}

// -------- kernel 4: quantize + transpose rhs -> q_rT [N][K] int8 --------
__global__ __launch_bounds__(256) void quant_rhs_t_kernel(
        const float* __restrict__ rhs, const float* __restrict__ sR,
        int8_t* __restrict__ qbT) {
    __shared__ __align__(16) int8_t lt[64][80];   // +16B pad: keeps rows 16B-aligned
    const int n0 = blockIdx.x * 64;
    const int k0 = blockIdx.y * 64;
    const int t = threadIdx.x;
    const int nloc = t & 63;
    const int kq = (t >> 6) * 16;
    const float s = sR[n0 + nloc];
#pragma unroll
    for (int i = 0; i < 4; ++i) {
        unsigned pack = 0;
#pragma unroll
        for (int j = 0; j < 4; ++j) {
            int kk = kq + i * 4 + j;
            float x = rhs[(size_t)(k0 + kk) * N_DIM + n0 + nloc]; // coalesced across lanes
            int q = (int)fminf(fmaxf(rintf(x / s), -QMAXF), QMAXF);
            pack |= (unsigned)(q & 255) << (8 * j);
        }
        *(unsigned*)&lt[nloc][kq + i * 4] = pack;
    }
    __syncthreads();
    const int nn = t >> 2, ch = t & 3;
    v4i val = *(const v4i*)&lt[nn][ch * 16];
    *(v4i*)&qbT[(size_t)(n0 + nn) * K_DIM + k0 + ch * 16] = val;
}

// ---------------- kernel 5: int8 MFMA GEMM + dequant epilogue ----------------
// C[m][n] = (sum_k qa[m][k]*qbT[n][k]) * sL[m] * sR[n]
// 128x128 tile, BK=64, 4 waves (2x2), each wave 64x64 = 4x4 frags of 16x16x64 i8.
__global__ __launch_bounds__(256, 2) void gemm_i8_kernel(
        const int8_t* __restrict__ qa, const int8_t* __restrict__ qbT,
        const float* __restrict__ sL, const float* __restrict__ sR,
        float* __restrict__ out) {
    __shared__ __align__(16) int8_t lds_a[128 * 64];
    __shared__ __align__(16) int8_t lds_b[128 * 64];

    const int t = threadIdx.x;
    const int wave = t >> 6;
    const int lane = t & 63;
    const int brow = blockIdx.y * 128;
    const int bcol = blockIdx.x * 128;
    const int wm = (wave >> 1) * 64;
    const int wn = (wave & 1) * 64;

    // Staging geometry: thread t owns LDS linear bytes [t*16, t*16+16) (+pass*4096).
    // LDS row r = t>>2 (+64*pass), physical chunk pc = t&3.
    // Swizzle: physical chunk pc holds logical chunk pc ^ ((r>>1)&3)  (inverse-swizzled source).
    const int srow = t >> 2;                       // 0..63
    const int pc = t & 3;
    const int cswz = pc ^ ((srow >> 1) & 3);       // same for pass 1: (+64)>>1 = +32 ≡ 0 mod 4

    // Fragment read byte-offsets (swizzled on read side)
    int a_off[4], b_off[4];
#pragma unroll
    for (int m = 0; m < 4; ++m) {
        int row = wm + m * 16 + (lane & 15);
        int pch = (lane >> 4) ^ ((row >> 1) & 3);
        a_off[m] = row * 64 + pch * 16;
    }
#pragma unroll
    for (int n = 0; n < 4; ++n) {
        int row = wn + n * 16 + (lane & 15);
        int pch = (lane >> 4) ^ ((row >> 1) & 3);
        b_off[n] = row * 64 + pch * 16;
    }

    v4i acc[4][4];
#pragma unroll
    for (int m = 0; m < 4; ++m)
#pragma unroll
        for (int n = 0; n < 4; ++n) acc[m][n] = (v4i){0, 0, 0, 0};

    const int8_t* gA = qa  + (size_t)(brow + srow) * K_DIM + cswz * 16;
    const int8_t* gB = qbT + (size_t)(bcol + srow) * K_DIM + cswz * 16;
    const size_t pass_stride = (size_t)64 * K_DIM;

    // wave-uniform LDS dest bases (HW scatters lane l at +l*16)
    int8_t* ldsA0 = lds_a + wave * 1024;
    int8_t* ldsA1 = lds_a + 4096 + wave * 1024;
    int8_t* ldsB0 = lds_b + wave * 1024;
    int8_t* ldsB1 = lds_b + 4096 + wave * 1024;

    for (int k0 = 0; k0 < K_DIM; k0 += 64) {
        __syncthreads();   // previous iteration's LDS reads complete before overwrite
        load_lds16(gA + k0,               ldsA0);
        load_lds16(gA + k0 + pass_stride, ldsA1);
        load_lds16(gB + k0,               ldsB0);
        load_lds16(gB + k0 + pass_stride, ldsB1);
        __syncthreads();   // emits s_waitcnt vmcnt(0) lgkmcnt(0) + s_barrier

        v4i af[4], bf[4];
#pragma unroll
        for (int m = 0; m < 4; ++m) af[m] = *(const v4i*)(lds_a + a_off[m]);
#pragma unroll
        for (int n = 0; n < 4; ++n) bf[n] = *(const v4i*)(lds_b + b_off[n]);
#pragma unroll
        for (int m = 0; m < 4; ++m)
#pragma unroll
            for (int n = 0; n < 4; ++n)
                acc[m][n] = __builtin_amdgcn_mfma_i32_16x16x64_i8(
                        af[m], bf[n], acc[m][n], 0, 0, 0);
    }

    // Epilogue: C/D layout (16x16): col = lane&15, row = (lane>>4)*4 + reg
    const int r4 = (lane >> 4) * 4;
    const int cc = lane & 15;
#pragma unroll
    for (int m = 0; m < 4; ++m) {
        const int grow0 = brow + wm + m * 16 + r4;
        const float s0 = sL[grow0 + 0];
        const float s1 = sL[grow0 + 1];
        const float s2 = sL[grow0 + 2];
        const float s3 = sL[grow0 + 3];
#pragma unroll
        for (int n = 0; n < 4; ++n) {
            const int gcol = bcol + wn + n * 16 + cc;
            const float sc = sR[gcol];
            float* o = out + (size_t)grow0 * N_DIM + gcol;
            o[0 * N_DIM] = (float)acc[m][n][0] * s0 * sc;
            o[1 * N_DIM] = (float)acc[m][n][1] * s1 * sc;
            o[2 * N_DIM] = (float)acc[m][n][2] * s2 * sc;
            o[3 * N_DIM] = (float)acc[m][n][3] * s3 * sc;
        }
    }
}

// ---------------- launch ----------------
extern "C" void kernel_launch(void* const* d_in, const int* in_sizes, int n_in,
                              void* d_out, int out_size, void* d_ws, size_t ws_size,
                              hipStream_t stream) {
    const float* lhs = (const float*)d_in[0];
    const float* rhs = (const float*)d_in[1];
    float* out = (float*)d_out;

    uint8_t* ws = (uint8_t*)d_ws;
    int8_t* ql    = (int8_t*)ws;                               // 33,554,432 B
    int8_t* qbT   = (int8_t*)(ws + 33554432);                  // 16,777,216 B
    float* sL     = (float*)(ws + 50331648);                   // 32,768 B
    float* sR     = (float*)(ws + 50331648 + 32768);           // 16,384 B
    unsigned* bits = (unsigned*)(ws + 50331648 + 32768 + 16384); // 16,384 B

    hipMemsetAsync(bits, 0, N_DIM * sizeof(unsigned), stream);

    row_scale_kernel<<<M_DIM, 256, 0, stream>>>(lhs, sL);
    col_absmax_kernel<<<dim3(N_DIM / 256, K_DIM / 64), 256, 0, stream>>>(rhs, bits);
    col_scale_kernel<<<N_DIM / 256, 256, 0, stream>>>(bits, sR);
    quant_lhs_kernel<<<(M_DIM * K_DIM / 4) / 256, 256, 0, stream>>>(lhs, sL, ql);
    quant_rhs_t_kernel<<<dim3(N_DIM / 64, K_DIM / 64), 256, 0, stream>>>(rhs, sR, qbT);
    gemm_i8_kernel<<<dim3(N_DIM / 128, M_DIM / 128), 256, 0, stream>>>(ql, qbT, sL, sR, out);
}

// Round 2
// 231.336 us; speedup vs baseline: 1.1116x; 1.1116x over previous
//
#include <hip/hip_runtime.h>
#include <stdint.h>

#define M_DIM 8192
#define N_DIM 4096
#define K_DIM 4096
#define QMAXF 127.0f
#define QDIVF 127.5f

typedef int v4i __attribute__((ext_vector_type(4)));

// ---------------- address-space helpers for global_load_lds ----------------
typedef __attribute__((address_space(3))) void lds_void_t;
typedef __attribute__((address_space(1))) const void glb_void_t;

static __device__ __forceinline__ void load_lds16(const void* g, void* l) {
    __builtin_amdgcn_global_load_lds((glb_void_t*)g, (lds_void_t*)l, 16, 0, 0);
}

// ---------------- kernel 1: per-row absmax -> scale (lhs) ----------------
__global__ __launch_bounds__(256) void row_scale_kernel(
        const float* __restrict__ lhs, float* __restrict__ sL) {
    const int row = blockIdx.x;
    const float4* rp = (const float4*)(lhs + (size_t)row * K_DIM);
    const int t = threadIdx.x;
    float m = 0.0f;
#pragma unroll
    for (int i = 0; i < 4; ++i) {
        float4 v = rp[t + i * 256];
        m = fmaxf(m, fmaxf(fmaxf(fabsf(v.x), fabsf(v.y)),
                           fmaxf(fabsf(v.z), fabsf(v.w))));
    }
#pragma unroll
    for (int off = 32; off; off >>= 1) m = fmaxf(m, __shfl_down(m, off, 64));
    __shared__ float wmax[4];
    if ((t & 63) == 0) wmax[t >> 6] = m;
    __syncthreads();
    if (t == 0) {
        float mm = fmaxf(fmaxf(wmax[0], wmax[1]), fmaxf(wmax[2], wmax[3]));
        float s = mm / QDIVF;
        sL[row] = (s == 0.0f) ? 1.0f : s;
    }
}

// ---------------- kernel 2a: per-col absmax partial (rhs) ----------------
__global__ __launch_bounds__(256) void col_absmax_kernel(
        const float* __restrict__ rhs, unsigned* __restrict__ bits) {
    const int col = blockIdx.x * 256 + threadIdx.x;
    const int r0 = blockIdx.y * 64;
    float m = 0.0f;
#pragma unroll 4
    for (int r = 0; r < 64; ++r)
        m = fmaxf(m, fabsf(rhs[(size_t)(r0 + r) * N_DIM + col]));
    atomicMax(&bits[col], __float_as_uint(m));   // abs values >= 0: bit order == float order
}

// ---------------- kernel 2b: bits -> scale ----------------
__global__ __launch_bounds__(256) void col_scale_kernel(
        const unsigned* __restrict__ bits, float* __restrict__ sR) {
    const int c = blockIdx.x * 256 + threadIdx.x;
    float s = __uint_as_float(bits[c]) / QDIVF;
    sR[c] = (s == 0.0f) ? 1.0f : s;
}

// ---------------- kernel 3: quantize lhs (row-major int8) ----------------
__global__ __launch_bounds__(256) void quant_lhs_kernel(
        const float* __restrict__ lhs, const float* __restrict__ sL,
        int8_t* __restrict__ ql) {
    const size_t idx = (size_t)blockIdx.x * 256 + threadIdx.x; // float4 index
    const int row = (int)(idx >> 10);                          // 1024 float4 per row
    const float s = sL[row];
    float4 v = ((const float4*)lhs)[idx];
    int q0 = (int)fminf(fmaxf(rintf(v.x / s), -QMAXF), QMAXF);
    int q1 = (int)fminf(fmaxf(rintf(v.y / s), -QMAXF), QMAXF);
    int q2 = (int)fminf(fmaxf(rintf(v.z / s), -QMAXF), QMAXF);
    int q3 = (int)fminf(fmaxf(rintf(v.w / s), -QMAXF), QMAXF);
    unsigned packed = (q0 & 255) | ((q1 & 255) << 8) | ((q2 & 255) << 16)
                    | ((unsigned)(q3 & 255) << 24);
    ((unsigned*)ql)[idx] = packed;
}

// -------- kernel 4: quantize + transpose rhs -> q_rT [N][K] int8 --------
__global__ __launch_bounds__(256) void quant_rhs_t_kernel(
        const float* __restrict__ rhs, const float* __restrict__ sR,
        int8_t* __restrict__ qbT) {
    __shared__ __align__(16) int8_t lt[64][80];   // +16B pad: keeps rows 16B-aligned
    const int n0 = blockIdx.x * 64;
    const int k0 = blockIdx.y * 64;
    const int t = threadIdx.x;
    const int nloc = t & 63;
    const int kq = (t >> 6) * 16;
    const float s = sR[n0 + nloc];
#pragma unroll
    for (int i = 0; i < 4; ++i) {
        unsigned pack = 0;
#pragma unroll
        for (int j = 0; j < 4; ++j) {
            int kk = kq + i * 4 + j;
            float x = rhs[(size_t)(k0 + kk) * N_DIM + n0 + nloc]; // coalesced across lanes
            int q = (int)fminf(fmaxf(rintf(x / s), -QMAXF), QMAXF);
            pack |= (unsigned)(q & 255) << (8 * j);
        }
        *(unsigned*)&lt[nloc][kq + i * 4] = pack;
    }
    __syncthreads();
    const int nn = t >> 2, ch = t & 3;
    v4i val = *(const v4i*)&lt[nn][ch * 16];
    *(v4i*)&qbT[(size_t)(n0 + nn) * K_DIM + k0 + ch * 16] = val;
}

// ============ kernel 5: int8 MFMA GEMM, 256x256 tile, 8-phase schedule ============
// C[m][n] = (sum_k qa[m][k]*qbT[n][k]) * sL[m] * sR[n]
// BM=BN=256, BK=128 bytes (int8), 8 waves (2M x 4N), per-wave 128x64 out.
// LDS 128 KiB: A[2 buf][256 rows][128 B] at 0, B same at 65536. Chunk-swizzled:
// 16B chunk pc holds logical chunk pc ^ (row&7)  (both-sides swizzle, rule #21).
// Per tile: 4 phases (mh,ks); each phase {ds_read subtile; 1 half-tile stage;
// barrier; 16 MFMA (setprio); barrier}. Counted vmcnt(2) once per tile at ph3.

#define BAR() do { asm volatile("" ::: "memory");          \
                   __builtin_amdgcn_s_barrier();           \
                   asm volatile("" ::: "memory"); } while (0)

#define STAGE_A(h, kt, p) do {                                                        \
    load_lds16(gA0 + (size_t)((h) * 128) * K_DIM + (size_t)(kt) * 128,                \
               lds + (p) * 32768 + (h) * 16384 + wb);                                 \
    load_lds16(gA0 + (size_t)((h) * 128 + 64) * K_DIM + (size_t)(kt) * 128,           \
               lds + (p) * 32768 + (h) * 16384 + 8192 + wb);                          \
} while (0)

#define STAGE_B(h, kt, p) do {                                                        \
    load_lds16(gB0 + (size_t)((h) * 128) * K_DIM + (size_t)(kt) * 128,                \
               lds + 65536 + (p) * 32768 + (h) * 16384 + wb);                         \
    load_lds16(gB0 + (size_t)((h) * 128 + 64) * K_DIM + (size_t)(kt) * 128,           \
               lds + 65536 + (p) * 32768 + (h) * 16384 + 8192 + wb);                  \
} while (0)

#define MFMA16(MB)                                                                    \
    _Pragma("unroll") for (int mm = 0; mm < 4; ++mm)                                  \
    _Pragma("unroll") for (int nn = 0; nn < 4; ++nn)                                  \
        acc[(MB) + mm][nn] = __builtin_amdgcn_mfma_i32_16x16x64_i8(                   \
            af[mm], bf[nn], acc[(MB) + mm][nn], 0, 0, 0);

#define TILE(TT, P, S1, S2) do {                                                      \
    /* ---- phase 0: (mh0, ks0); stage B1(TT+1) ---- */                               \
    _Pragma("unroll") for (int nn = 0; nn < 4; ++nn)                                  \
        bf[nn] = *(const v4i*)(lds + (P) * 32768 + boff[nn * 2 + 0]);                 \
    _Pragma("unroll") for (int mm = 0; mm < 4; ++mm)                                  \
        af[mm] = *(const v4i*)(lds + (P) * 32768 + aoff[mm * 2 + 0]);                 \
    if (S1) STAGE_B(1, (TT) + 1, (P) ^ 1);                                            \
    BAR();                                                                            \
    __builtin_amdgcn_s_setprio(1); MFMA16(0); __builtin_amdgcn_s_setprio(0);          \
    BAR();                                                                            \
    /* ---- phase 1: (mh1, ks0); stage A0(TT+1) ---- */                               \
    _Pragma("unroll") for (int mm = 0; mm < 4; ++mm)                                  \
        af[mm] = *(const v4i*)(lds + (P) * 32768 + aoff[(4 + mm) * 2 + 0]);           \
    if (S1) STAGE_A(0, (TT) + 1, (P) ^ 1);                                            \
    BAR();                                                                            \
    __builtin_amdgcn_s_setprio(1); MFMA16(4); __builtin_amdgcn_s_setprio(0);          \
    BAR();                                                                            \
    /* ---- phase 2: (mh0, ks1); stage A1(TT+1) ---- */                               \
    _Pragma("unroll") for (int nn = 0; nn < 4; ++nn)                                  \
        bf[nn] = *(const v4i*)(lds + (P) * 32768 + boff[nn * 2 + 1]);                 \
    _Pragma("unroll") for (int mm = 0; mm < 4; ++mm)                                  \
        af[mm] = *(const v4i*)(lds + (P) * 32768 + aoff[mm * 2 + 1]);                 \
    if (S1) STAGE_A(1, (TT) + 1, (P) ^ 1);                                            \
    BAR();                                                                            \
    __builtin_amdgcn_s_setprio(1); MFMA16(0); __builtin_amdgcn_s_setprio(0);          \
    BAR();                                                                            \
    /* ---- phase 3: (mh1, ks1); stage B0(TT+2); counted vmcnt ---- */                \
    _Pragma("unroll") for (int mm = 0; mm < 4; ++mm)                                  \
        af[mm] = *(const v4i*)(lds + (P) * 32768 + aoff[(4 + mm) * 2 + 1]);           \
    if (S2) {                                                                         \
        STAGE_B(0, (TT) + 2, (P));                                                    \
        asm volatile("s_waitcnt vmcnt(2)" ::: "memory");                              \
    } else {                                                                          \
        asm volatile("s_waitcnt vmcnt(0)" ::: "memory");                              \
    }                                                                                 \
    BAR();                                                                            \
    __builtin_amdgcn_s_setprio(1); MFMA16(4); __builtin_amdgcn_s_setprio(0);          \
    BAR();                                                                            \
} while (0)

__global__ __launch_bounds__(512, 2) void gemm_i8_kernel(
        const int8_t* __restrict__ qa, const int8_t* __restrict__ qbT,
        const float* __restrict__ sL, const float* __restrict__ sR,
        float* __restrict__ out) {
    __shared__ __align__(16) int8_t lds[131072];

    const int t = threadIdx.x;
    const int wave = t >> 6;
    const int lane = t & 63;

    // bijective XCD swizzle (512 blocks, 512 % 8 == 0)
    const int bid = blockIdx.x;
    const int swz = (bid & 7) * 64 + (bid >> 3);
    const int brow = (swz & 31) * 256;   // 32 M-tiles
    const int bcol = (swz >> 5) * 256;   // 16 N-tiles

    const int wm = (wave >> 2) * 128;
    const int wn = (wave & 3) * 64;

    // fragment read byte-offsets (swizzled): frag (m|n, ks), logical chunk ks*4+(lane>>4)
    int aoff[16];
    int boff[8];
#pragma unroll
    for (int m = 0; m < 8; ++m) {
        int row = wm + m * 16 + (lane & 15);
#pragma unroll
        for (int ks = 0; ks < 2; ++ks)
            aoff[m * 2 + ks] = row * 128 + ((ks * 4 + (lane >> 4)) ^ (row & 7)) * 16;
    }
#pragma unroll
    for (int n = 0; n < 4; ++n) {
        int row = wn + n * 16 + (lane & 15);
#pragma unroll
        for (int ks = 0; ks < 2; ++ks)
            boff[n * 2 + ks] = 65536 + row * 128 + ((ks * 4 + (lane >> 4)) ^ (row & 7)) * 16;
    }

    v4i acc[8][4];
#pragma unroll
    for (int m = 0; m < 8; ++m)
#pragma unroll
        for (int n = 0; n < 4; ++n) acc[m][n] = (v4i){0, 0, 0, 0};

    // staging: thread t covers LDS bytes [t*16, t*16+16) of each 8KB chunk;
    // source column pre-swizzled so linear LDS holds the swizzled layout.
    const int srow = t >> 3;                               // 0..63
    const int scol = ((t & 7) ^ (srow & 7)) * 16;
    const int8_t* gA0 = qa  + (size_t)(brow + srow) * K_DIM + scol;
    const int8_t* gB0 = qbT + (size_t)(bcol + srow) * K_DIM + scol;
    const int wb = (t >> 6) * 1024;                        // wave-uniform LDS base part

    v4i af[4], bf[4];

    // prologue: tile0 complete (8 loads) + B0(tile1) (2 loads); wait oldest 8
    STAGE_B(0, 0, 0);
    STAGE_B(1, 0, 0);
    STAGE_A(0, 0, 0);
    STAGE_A(1, 0, 0);
    STAGE_B(0, 1, 1);
    asm volatile("s_waitcnt vmcnt(2)" ::: "memory");
    BAR();

    for (int tt = 0; tt < 30; tt += 2) {
        TILE(tt, 0, 1, 1);
        TILE(tt + 1, 1, 1, 1);
    }
    TILE(30, 0, 1, 0);   // stages tile31 remnants; ph3 drains vmcnt(0)
    TILE(31, 1, 0, 0);   // no stages

    // Epilogue: C/D layout (16x16): col = lane&15, row = (lane>>4)*4 + reg
    const int r4 = (lane >> 4) * 4;
    const int cc = lane & 15;
#pragma unroll
    for (int m = 0; m < 8; ++m) {
        const int grow0 = brow + wm + m * 16 + r4;
        const float s0 = sL[grow0 + 0];
        const float s1 = sL[grow0 + 1];
        const float s2 = sL[grow0 + 2];
        const float s3 = sL[grow0 + 3];
#pragma unroll
        for (int n = 0; n < 4; ++n) {
            const int gcol = bcol + wn + n * 16 + cc;
            const float sc = sR[gcol];
            float* o = out + (size_t)grow0 * N_DIM + gcol;
            o[0 * N_DIM] = (float)acc[m][n][0] * s0 * sc;
            o[1 * N_DIM] = (float)acc[m][n][1] * s1 * sc;
            o[2 * N_DIM] = (float)acc[m][n][2] * s2 * sc;
            o[3 * N_DIM] = (float)acc[m][n][3] * s3 * sc;
        }
    }
}

// ---------------- launch ----------------
extern "C" void kernel_launch(void* const* d_in, const int* in_sizes, int n_in,
                              void* d_out, int out_size, void* d_ws, size_t ws_size,
                              hipStream_t stream) {
    const float* lhs = (const float*)d_in[0];
    const float* rhs = (const float*)d_in[1];
    float* out = (float*)d_out;

    uint8_t* ws = (uint8_t*)d_ws;
    int8_t* ql    = (int8_t*)ws;                               // 33,554,432 B
    int8_t* qbT   = (int8_t*)(ws + 33554432);                  // 16,777,216 B
    float* sL     = (float*)(ws + 50331648);                   // 32,768 B
    float* sR     = (float*)(ws + 50331648 + 32768);           // 16,384 B
    unsigned* bits = (unsigned*)(ws + 50331648 + 32768 + 16384); // 16,384 B

    hipMemsetAsync(bits, 0, N_DIM * sizeof(unsigned), stream);

    row_scale_kernel<<<M_DIM, 256, 0, stream>>>(lhs, sL);
    col_absmax_kernel<<<dim3(N_DIM / 256, K_DIM / 64), 256, 0, stream>>>(rhs, bits);
    col_scale_kernel<<<N_DIM / 256, 256, 0, stream>>>(bits, sR);
    quant_lhs_kernel<<<(M_DIM * K_DIM / 4) / 256, 256, 0, stream>>>(lhs, sL, ql);
    quant_rhs_t_kernel<<<dim3(N_DIM / 64, K_DIM / 64), 256, 0, stream>>>(rhs, sR, qbT);
    gemm_i8_kernel<<<dim3(M_DIM / 256 * N_DIM / 256), 512, 0, stream>>>(ql, qbT, sL, sR, out);
}

// Round 3
// 223.597 us; speedup vs baseline: 1.1500x; 1.0346x over previous
//
#include <hip/hip_runtime.h>
#include <stdint.h>

#define M_DIM 8192
#define N_DIM 4096
#define K_DIM 4096
#define QMAXF 127.0f
#define QDIVF 127.5f

typedef int v4i __attribute__((ext_vector_type(4)));

// ---------------- address-space helpers for global_load_lds ----------------
typedef __attribute__((address_space(3))) void lds_void_t;
typedef __attribute__((address_space(1))) const void glb_void_t;

static __device__ __forceinline__ void load_lds16(const void* g, void* l) {
    __builtin_amdgcn_global_load_lds((glb_void_t*)g, (lds_void_t*)l, 16, 0, 0);
}

// ------- kernel 1: fused per-row absmax + quantize lhs (single pass) -------
// One block per row; row (16 KB) held in 16 regs/thread -> lhs read ONCE.
__global__ __launch_bounds__(256) void row_quant_kernel(
        const float* __restrict__ lhs, float* __restrict__ sL,
        int8_t* __restrict__ ql) {
    const int row = blockIdx.x;
    const float4* rp = (const float4*)(lhs + (size_t)row * K_DIM);
    const int t = threadIdx.x;
    float4 v[4];
    float m = 0.0f;
#pragma unroll
    for (int i = 0; i < 4; ++i) {
        v[i] = rp[t + i * 256];
        m = fmaxf(m, fmaxf(fmaxf(fabsf(v[i].x), fabsf(v[i].y)),
                           fmaxf(fabsf(v[i].z), fabsf(v[i].w))));
    }
#pragma unroll
    for (int off = 32; off; off >>= 1) m = fmaxf(m, __shfl_down(m, off, 64));
    __shared__ float wmax[4];
    if ((t & 63) == 0) wmax[t >> 6] = m;
    __syncthreads();
    const float mm = fmaxf(fmaxf(wmax[0], wmax[1]), fmaxf(wmax[2], wmax[3]));
    float s = mm / QDIVF;
    s = (s == 0.0f) ? 1.0f : s;
    if (t == 0) sL[row] = s;
    unsigned* qo = (unsigned*)ql + (size_t)row * 1024;
#pragma unroll
    for (int i = 0; i < 4; ++i) {
        int q0 = (int)fminf(fmaxf(rintf(v[i].x / s), -QMAXF), QMAXF);
        int q1 = (int)fminf(fmaxf(rintf(v[i].y / s), -QMAXF), QMAXF);
        int q2 = (int)fminf(fmaxf(rintf(v[i].z / s), -QMAXF), QMAXF);
        int q3 = (int)fminf(fmaxf(rintf(v[i].w / s), -QMAXF), QMAXF);
        qo[t + i * 256] = (q0 & 255) | ((q1 & 255) << 8) | ((q2 & 255) << 16)
                        | ((unsigned)(q3 & 255) << 24);
    }
}

// ---------------- kernel 2a: per-col absmax partial (rhs) ----------------
__global__ __launch_bounds__(256) void col_absmax_kernel(
        const float* __restrict__ rhs, unsigned* __restrict__ bits) {
    const int col = blockIdx.x * 256 + threadIdx.x;
    const int r0 = blockIdx.y * 64;
    float m = 0.0f;
#pragma unroll 4
    for (int r = 0; r < 64; ++r)
        m = fmaxf(m, fabsf(rhs[(size_t)(r0 + r) * N_DIM + col]));
    atomicMax(&bits[col], __float_as_uint(m));   // abs values >= 0: bit order == float order
}

// ---------------- kernel 2b: bits -> scale ----------------
__global__ __launch_bounds__(256) void col_scale_kernel(
        const unsigned* __restrict__ bits, float* __restrict__ sR) {
    const int c = blockIdx.x * 256 + threadIdx.x;
    float s = __uint_as_float(bits[c]) / QDIVF;
    sR[c] = (s == 0.0f) ? 1.0f : s;
}

// -------- kernel 4: quantize + transpose rhs -> q_rT [N][K] int8 --------
__global__ __launch_bounds__(256) void quant_rhs_t_kernel(
        const float* __restrict__ rhs, const float* __restrict__ sR,
        int8_t* __restrict__ qbT) {
    __shared__ __align__(16) int8_t lt[64][80];
    const int n0 = blockIdx.x * 64;
    const int k0 = blockIdx.y * 64;
    const int t = threadIdx.x;
    const int nloc = t & 63;
    const int kq = (t >> 6) * 16;
    const float s = sR[n0 + nloc];
#pragma unroll
    for (int i = 0; i < 4; ++i) {
        unsigned pack = 0;
#pragma unroll
        for (int j = 0; j < 4; ++j) {
            int kk = kq + i * 4 + j;
            float x = rhs[(size_t)(k0 + kk) * N_DIM + n0 + nloc];
            int q = (int)fminf(fmaxf(rintf(x / s), -QMAXF), QMAXF);
            pack |= (unsigned)(q & 255) << (8 * j);
        }
        *(unsigned*)&lt[nloc][kq + i * 4] = pack;
    }
    __syncthreads();
    const int nn = t >> 2, ch = t & 3;
    v4i val = *(const v4i*)&lt[nn][ch * 16];
    *(v4i*)&qbT[(size_t)(n0 + nn) * K_DIM + k0 + ch * 16] = val;
}

// ============ kernel 5: int8 MFMA GEMM, 256x256 tile, BK=64, 4-deep ring ============
// C[m][n] = (sum_k qa[m][k]*qbT[n][k]) * sL[m] * sR[n]
// 8 waves (4M x 2N), per-wave 64x128 out = acc[4][8]. Tile = K=64 (64B rows).
// LDS ring of 4 tile-buffers (A 16KB + B 16KB each) = 128 KiB.
// Prefetch 3 tiles ahead (1 half-tile pair per phase); counted vmcnt(8) once
// per tile -> each tile's loads get ~4 phases (~2600 cy) to land.
// 16B-chunk swizzle pc = lc ^ ((row>>1)&3), applied on BOTH source addr and
// ds_read (rule #21); residual 2-way conflict is free (m136).

#define BAR() do { asm volatile("" ::: "memory");          \
                   __builtin_amdgcn_s_barrier();           \
                   asm volatile("" ::: "memory"); } while (0)

#define VMCNT(N) asm volatile("s_waitcnt vmcnt(%0)" :: "n"(N) : "memory")

// one global_load_lds per thread = one 8KB half (128 rows x 64B)
#define STAGE_A(h, kt, bq) \
    load_lds16(gA0 + (size_t)((h) * 128) * K_DIM + (size_t)(kt) * 64, \
               lds + (bq) * 16384 + (h) * 8192 + sdst)
#define STAGE_B(h, kt, bq) \
    load_lds16(gB0 + (size_t)((h) * 128) * K_DIM + (size_t)(kt) * 64, \
               lds + 65536 + (bq) * 16384 + (h) * 8192 + sdst)

#define MFMA16(NB)                                                              \
    _Pragma("unroll") for (int mm = 0; mm < 4; ++mm)                            \
    _Pragma("unroll") for (int nn = 0; nn < 4; ++nn)                            \
        acc[mm][(NB) + nn] = __builtin_amdgcn_mfma_i32_16x16x64_i8(             \
            af[mm], bf[nn], acc[mm][(NB) + nn], 0, 0, 0);

// TILE: BUF = KT & 3 (compile-time); S = stage tile KT+3; VM = vmcnt arg
#define TILE(KT, BUF, S, VM) do {                                               \
    /* phase 0: read af0-3, bf0-3; stage A halves of KT+3 */                    \
    _Pragma("unroll") for (int mm = 0; mm < 4; ++mm)                            \
        af[mm] = *(const v4i*)(lds + (BUF) * 16384 + aoff[mm]);                 \
    _Pragma("unroll") for (int nn = 0; nn < 4; ++nn)                            \
        bf[nn] = *(const v4i*)(lds + (BUF) * 16384 + boff[nn]);                 \
    if (S) { STAGE_A(0, (KT) + 3, ((BUF) + 3) & 3);                             \
             STAGE_A(1, (KT) + 3, ((BUF) + 3) & 3); }                           \
    BAR();                                                                      \
    __builtin_amdgcn_s_setprio(1); MFMA16(0); __builtin_amdgcn_s_setprio(0);    \
    BAR();                                                                      \
    /* phase 1: read bf4-7; stage B halves of KT+3; counted wait */             \
    _Pragma("unroll") for (int nn = 0; nn < 4; ++nn)                            \
        bf[nn] = *(const v4i*)(lds + (BUF) * 16384 + boff[4 + nn]);             \
    if (S) { STAGE_B(0, (KT) + 3, ((BUF) + 3) & 3);                             \
             STAGE_B(1, (KT) + 3, ((BUF) + 3) & 3); }                           \
    VMCNT(VM);                                                                  \
    BAR();                                                                      \
    __builtin_amdgcn_s_setprio(1); MFMA16(4); __builtin_amdgcn_s_setprio(0);    \
    BAR();                                                                      \
} while (0)

__global__ __launch_bounds__(512, 2) void gemm_i8_kernel(
        const int8_t* __restrict__ qa, const int8_t* __restrict__ qbT,
        const float* __restrict__ sL, const float* __restrict__ sR,
        float* __restrict__ out) {
    __shared__ __align__(16) int8_t lds[131072];

    const int t = threadIdx.x;
    const int wave = t >> 6;
    const int lane = t & 63;

    // bijective XCD swizzle (512 blocks, 512 % 8 == 0)
    const int bid = blockIdx.x;
    const int swz = (bid & 7) * 64 + (bid >> 3);
    const int brow = (swz & 31) * 256;   // 32 M-tiles
    const int bcol = (swz >> 5) * 256;   // 16 N-tiles

    const int wm = (wave >> 1) * 64;     // 4 M-groups
    const int wn = (wave & 1) * 128;     // 2 N-groups

    // fragment read byte-offsets (swizzled); rows are 64B
    int aoff[4], boff[8];
#pragma unroll
    for (int m = 0; m < 4; ++m) {
        int row = wm + m * 16 + (lane & 15);
        aoff[m] = row * 64 + (((lane >> 4) ^ ((row >> 1) & 3)) * 16);
    }
#pragma unroll
    for (int n = 0; n < 8; ++n) {
        int row = wn + n * 16 + (lane & 15);
        boff[n] = 65536 + row * 64 + (((lane >> 4) ^ ((row >> 1) & 3)) * 16);
    }

    v4i acc[4][8];
#pragma unroll
    for (int m = 0; m < 4; ++m)
#pragma unroll
        for (int n = 0; n < 8; ++n) acc[m][n] = (v4i){0, 0, 0, 0};

    // staging: thread t covers bytes [t*16, t*16+16) of an 8KB half-tile.
    // source column pre-swizzled so linear LDS holds the swizzled layout.
    const int srow = t >> 2;                                  // 0..127
    const int lc = (t & 3) ^ ((srow >> 1) & 3);               // logical chunk
    const int8_t* gA0 = qa  + (size_t)(brow + srow) * K_DIM + lc * 16;
    const int8_t* gB0 = qbT + (size_t)(bcol + srow) * K_DIM + lc * 16;
    const int sdst = t * 16;

    v4i af[4], bf[4];

    // prologue: stage tiles 0,1,2 (tile-monotone order), wait tile 0
    STAGE_A(0, 0, 0); STAGE_A(1, 0, 0); STAGE_B(0, 0, 0); STAGE_B(1, 0, 0);
    STAGE_A(0, 1, 1); STAGE_A(1, 1, 1); STAGE_B(0, 1, 1); STAGE_B(1, 1, 1);
    STAGE_A(0, 2, 2); STAGE_A(1, 2, 2); STAGE_B(0, 2, 2); STAGE_B(1, 2, 2);
    VMCNT(8);
    BAR();

    for (int kt = 0; kt < 60; kt += 4) {
        TILE(kt + 0, 0, 1, 8);
        TILE(kt + 1, 1, 1, 8);
        TILE(kt + 2, 2, 1, 8);
        TILE(kt + 3, 3, 1, 8);
    }
    TILE(60, 0, 1, 8);   // stages tile 63
    TILE(61, 1, 0, 4);   // need tile 62 landed; tile 63's 4 may stay in flight
    TILE(62, 2, 0, 0);
    TILE(63, 3, 0, 0);

    // Epilogue: C/D layout (16x16): col = lane&15, row = (lane>>4)*4 + reg
    const int r4 = (lane >> 4) * 4;
    const int cc = lane & 15;
#pragma unroll
    for (int m = 0; m < 4; ++m) {
        const int grow0 = brow + wm + m * 16 + r4;
        const float s0 = sL[grow0 + 0];
        const float s1 = sL[grow0 + 1];
        const float s2 = sL[grow0 + 2];
        const float s3 = sL[grow0 + 3];
#pragma unroll
        for (int n = 0; n < 8; ++n) {
            const int gcol = bcol + wn + n * 16 + cc;
            const float sc = sR[gcol];
            float* o = out + (size_t)grow0 * N_DIM + gcol;
            o[0 * N_DIM] = (float)acc[m][n][0] * s0 * sc;
            o[1 * N_DIM] = (float)acc[m][n][1] * s1 * sc;
            o[2 * N_DIM] = (float)acc[m][n][2] * s2 * sc;
            o[3 * N_DIM] = (float)acc[m][n][3] * s3 * sc;
        }
    }
}

// ---------------- launch ----------------
extern "C" void kernel_launch(void* const* d_in, const int* in_sizes, int n_in,
                              void* d_out, int out_size, void* d_ws, size_t ws_size,
                              hipStream_t stream) {
    const float* lhs = (const float*)d_in[0];
    const float* rhs = (const float*)d_in[1];
    float* out = (float*)d_out;

    uint8_t* ws = (uint8_t*)d_ws;
    int8_t* ql    = (int8_t*)ws;                               // 33,554,432 B
    int8_t* qbT   = (int8_t*)(ws + 33554432);                  // 16,777,216 B
    float* sL     = (float*)(ws + 50331648);                   // 32,768 B
    float* sR     = (float*)(ws + 50331648 + 32768);           // 16,384 B
    unsigned* bits = (unsigned*)(ws + 50331648 + 32768 + 16384); // 16,384 B

    hipMemsetAsync(bits, 0, N_DIM * sizeof(unsigned), stream);

    row_quant_kernel<<<M_DIM, 256, 0, stream>>>(lhs, sL, ql);
    col_absmax_kernel<<<dim3(N_DIM / 256, K_DIM / 64), 256, 0, stream>>>(rhs, bits);
    col_scale_kernel<<<N_DIM / 256, 256, 0, stream>>>(bits, sR);
    quant_rhs_t_kernel<<<dim3(N_DIM / 64, K_DIM / 64), 256, 0, stream>>>(rhs, sR, qbT);
    gemm_i8_kernel<<<dim3(M_DIM / 256 * N_DIM / 256), 512, 0, stream>>>(ql, qbT, sL, sR, out);
}

// Round 5
// 220.203 us; speedup vs baseline: 1.1678x; 1.0154x over previous
//
#include <hip/hip_runtime.h>
#include <stdint.h>

#define M_DIM 8192
#define N_DIM 4096
#define K_DIM 4096
#define QMAXF 127.0f
#define QDIVF 127.5f

typedef int v4i __attribute__((ext_vector_type(4)));

// ---------------- address-space helpers for global_load_lds ----------------
typedef __attribute__((address_space(3))) void lds_void_t;
typedef __attribute__((address_space(1))) const void glb_void_t;

static __device__ __forceinline__ void load_lds16(const void* g, void* l) {
    __builtin_amdgcn_global_load_lds((glb_void_t*)g, (lds_void_t*)l, 16, 0, 0);
}

// ------- kernel 1: fused per-row absmax + quantize lhs (single pass) -------
__global__ __launch_bounds__(256) void row_quant_kernel(
        const float* __restrict__ lhs, float* __restrict__ sL,
        int8_t* __restrict__ ql) {
    const int row = blockIdx.x;
    const float4* rp = (const float4*)(lhs + (size_t)row * K_DIM);
    const int t = threadIdx.x;
    float4 v[4];
    float m = 0.0f;
#pragma unroll
    for (int i = 0; i < 4; ++i) {
        v[i] = rp[t + i * 256];
        m = fmaxf(m, fmaxf(fmaxf(fabsf(v[i].x), fabsf(v[i].y)),
                           fmaxf(fabsf(v[i].z), fabsf(v[i].w))));
    }
#pragma unroll
    for (int off = 32; off; off >>= 1) m = fmaxf(m, __shfl_down(m, off, 64));
    __shared__ float wmax[4];
    if ((t & 63) == 0) wmax[t >> 6] = m;
    __syncthreads();
    const float mm = fmaxf(fmaxf(wmax[0], wmax[1]), fmaxf(wmax[2], wmax[3]));
    float s = mm / QDIVF;
    s = (s == 0.0f) ? 1.0f : s;
    if (t == 0) sL[row] = s;
    unsigned* qo = (unsigned*)ql + (size_t)row * 1024;
#pragma unroll
    for (int i = 0; i < 4; ++i) {
        int q0 = (int)fminf(fmaxf(rintf(v[i].x / s), -QMAXF), QMAXF);
        int q1 = (int)fminf(fmaxf(rintf(v[i].y / s), -QMAXF), QMAXF);
        int q2 = (int)fminf(fmaxf(rintf(v[i].z / s), -QMAXF), QMAXF);
        int q3 = (int)fminf(fmaxf(rintf(v[i].w / s), -QMAXF), QMAXF);
        qo[t + i * 256] = (q0 & 255) | ((q1 & 255) << 8) | ((q2 & 255) << 16)
                        | ((unsigned)(q3 & 255) << 24);
    }
}

// ---------------- kernel 2a: per-col absmax partial (rhs) ----------------
__global__ __launch_bounds__(256) void col_absmax_kernel(
        const float* __restrict__ rhs, unsigned* __restrict__ bits) {
    const int col = blockIdx.x * 256 + threadIdx.x;
    const int r0 = blockIdx.y * 64;
    float m = 0.0f;
#pragma unroll 4
    for (int r = 0; r < 64; ++r)
        m = fmaxf(m, fabsf(rhs[(size_t)(r0 + r) * N_DIM + col]));
    atomicMax(&bits[col], __float_as_uint(m));
}

// ---------------- kernel 2b: bits -> scale ----------------
__global__ __launch_bounds__(256) void col_scale_kernel(
        const unsigned* __restrict__ bits, float* __restrict__ sR) {
    const int c = blockIdx.x * 256 + threadIdx.x;
    float s = __uint_as_float(bits[c]) / QDIVF;
    sR[c] = (s == 0.0f) ? 1.0f : s;
}

// -------- kernel 4: quantize + transpose rhs -> q_rT [N][K] int8 --------
__global__ __launch_bounds__(256) void quant_rhs_t_kernel(
        const float* __restrict__ rhs, const float* __restrict__ sR,
        int8_t* __restrict__ qbT) {
    __shared__ __align__(16) int8_t lt[64][80];
    const int n0 = blockIdx.x * 64;
    const int k0 = blockIdx.y * 64;
    const int t = threadIdx.x;
    const int nloc = t & 63;
    const int kq = (t >> 6) * 16;
    const float s = sR[n0 + nloc];
#pragma unroll
    for (int i = 0; i < 4; ++i) {
        unsigned pack = 0;
#pragma unroll
        for (int j = 0; j < 4; ++j) {
            int kk = kq + i * 4 + j;
            float x = rhs[(size_t)(k0 + kk) * N_DIM + n0 + nloc];
            int q = (int)fminf(fmaxf(rintf(x / s), -QMAXF), QMAXF);
            pack |= (unsigned)(q & 255) << (8 * j);
        }
        *(unsigned*)&lt[nloc][kq + i * 4] = pack;
    }
    __syncthreads();
    const int nn = t >> 2, ch = t & 3;
    v4i val = *(const v4i*)&lt[nn][ch * 16];
    *(v4i*)&qbT[(size_t)(n0 + nn) * K_DIM + k0 + ch * 16] = val;
}

// ====== kernel 5: int8 GEMM, 256x256 tile, BK=64, ring-4, 1 barrier/tile ======
// mfma_i32_16x16x64_i8 (R2/R3-validated fragments & epilogue).
// Schedule invariant: at the barrier ending tile KT, tiles <= KT+2 are landed
// in LDS for ALL waves (VMCNT(4) before the barrier drains tile KT+2).
// So inside tile KT it is race-free to read: tile KT fragments (landed 2 bars
// ago) and tile KT+1 fragments (landed at last bar). Reads for the next
// cluster/tile are issued BETWEEN MFMA clusters -> LDS service hides under MFMA.
// WAR: stage of KT+3 overwrites tile KT-1's buffer; all reads of it completed
// before the previous barrier (consumed by MFMA via lgkmcnt). 

#define BAR() do { asm volatile("" ::: "memory");          \
                   __builtin_amdgcn_s_barrier();           \
                   asm volatile("" ::: "memory"); } while (0)

#define VMCNT(N) asm volatile("s_waitcnt vmcnt(%0)" :: "n"(N) : "memory")

#define STAGE_A(h, kt, bq) \
    load_lds16(gA0 + (size_t)((h) * 128) * K_DIM + (size_t)(kt) * 64, \
               lds + (bq) * 16384 + (h) * 8192 + sdst)
#define STAGE_B(h, kt, bq) \
    load_lds16(gB0 + (size_t)((h) * 128) * K_DIM + (size_t)(kt) * 64, \
               lds + 65536 + (bq) * 16384 + (h) * 8192 + sdst)

#define RD_A(BUF, MM) (*(const v4i*)(lds + (BUF) * 16384 + aoff[MM]))
#define RD_B(BUF, NN) (*(const v4i*)(lds + (BUF) * 16384 + boff[NN]))

// TILE: BUF = KT & 3, P = KT & 1 (both compile-time). S: stage KT+3.
// RDN: read tile KT+1 fragments. VM: counted vmcnt before barrier.
#define TILE(KT, BUF, P, S, VM, RDN) do {                                       \
    _Pragma("unroll") for (int nn = 0; nn < 4; ++nn)                            \
        bfII[nn] = RD_B(BUF, 4 + nn);                                           \
    if (S) { STAGE_A(0, (KT) + 3, ((BUF) + 3) & 3);                             \
             STAGE_A(1, (KT) + 3, ((BUF) + 3) & 3);                             \
             STAGE_B(0, (KT) + 3, ((BUF) + 3) & 3);                             \
             STAGE_B(1, (KT) + 3, ((BUF) + 3) & 3); }                           \
    __builtin_amdgcn_s_setprio(1);                                              \
    _Pragma("unroll") for (int mm = 0; mm < 4; ++mm)                            \
    _Pragma("unroll") for (int nn = 0; nn < 4; ++nn)                            \
        acc[mm][nn] = __builtin_amdgcn_mfma_i32_16x16x64_i8(                    \
            af[P][mm], bfI[P][nn], acc[mm][nn], 0, 0, 0);                       \
    __builtin_amdgcn_s_setprio(0);                                              \
    if (RDN) {                                                                  \
        _Pragma("unroll") for (int mm = 0; mm < 4; ++mm)                        \
            af[(P) ^ 1][mm] = RD_A(((BUF) + 1) & 3, mm);                        \
        _Pragma("unroll") for (int nn = 0; nn < 4; ++nn)                        \
            bfI[(P) ^ 1][nn] = RD_B(((BUF) + 1) & 3, nn);                       \
    }                                                                           \
    __builtin_amdgcn_s_setprio(1);                                              \
    _Pragma("unroll") for (int mm = 0; mm < 4; ++mm)                            \
    _Pragma("unroll") for (int nn = 0; nn < 4; ++nn)                            \
        acc[mm][4 + nn] = __builtin_amdgcn_mfma_i32_16x16x64_i8(                \
            af[P][mm], bfII[nn], acc[mm][4 + nn], 0, 0, 0);                     \
    __builtin_amdgcn_s_setprio(0);                                              \
    VMCNT(VM);                                                                  \
    BAR();                                                                      \
} while (0)

__global__ __launch_bounds__(512, 2) void gemm_i8_kernel(
        const int8_t* __restrict__ qa, const int8_t* __restrict__ qbT,
        const float* __restrict__ sL, const float* __restrict__ sR,
        float* __restrict__ out) {
    __shared__ __align__(16) int8_t lds[131072];

    const int t = threadIdx.x;
    const int wave = t >> 6;
    const int lane = t & 63;

    // bijective XCD swizzle (512 blocks % 8 == 0)
    const int bid = blockIdx.x;
    const int swz = (bid & 7) * 64 + (bid >> 3);
    const int brow = (swz & 31) * 256;
    const int bcol = (swz >> 5) * 256;

    const int wm = (wave >> 1) * 64;     // 4 M-groups of 64 rows
    const int wn = (wave & 1) * 128;     // 2 N-groups of 128 cols

    // fragment read byte-offsets (swizzled); rows are 64B (R3-validated)
    int aoff[4], boff[8];
#pragma unroll
    for (int m = 0; m < 4; ++m) {
        int row = wm + m * 16 + (lane & 15);
        aoff[m] = row * 64 + (((lane >> 4) ^ ((row >> 1) & 3)) * 16);
    }
#pragma unroll
    for (int n = 0; n < 8; ++n) {
        int row = wn + n * 16 + (lane & 15);
        boff[n] = 65536 + row * 64 + (((lane >> 4) ^ ((row >> 1) & 3)) * 16);
    }

    v4i acc[4][8];
#pragma unroll
    for (int m = 0; m < 4; ++m)
#pragma unroll
        for (int n = 0; n < 8; ++n) acc[m][n] = (v4i){0, 0, 0, 0};

    // staging: thread t covers bytes [t*16, t*16+16) of an 8KB half-tile
    const int srow = t >> 2;                                  // 0..127
    const int lc = (t & 3) ^ ((srow >> 1) & 3);               // pre-swizzled source chunk
    const int8_t* gA0 = qa  + (size_t)(brow + srow) * K_DIM + lc * 16;
    const int8_t* gB0 = qbT + (size_t)(bcol + srow) * K_DIM + lc * 16;
    const int sdst = t * 16;

    v4i af[2][4], bfI[2][4], bfII[4];

    // prologue: stage tiles 0,1,2 (tile-monotone order); drain T0,T1 for all
    // waves (VMCNT then BARRIER) BEFORE any LDS read -> no cross-wave race.
    STAGE_A(0, 0, 0); STAGE_A(1, 0, 0); STAGE_B(0, 0, 0); STAGE_B(1, 0, 0);
    STAGE_A(0, 1, 1); STAGE_A(1, 1, 1); STAGE_B(0, 1, 1); STAGE_B(1, 1, 1);
    STAGE_A(0, 2, 2); STAGE_A(1, 2, 2); STAGE_B(0, 2, 2); STAGE_B(1, 2, 2);
    VMCNT(4);
    BAR();
#pragma unroll
    for (int mm = 0; mm < 4; ++mm) af[0][mm] = RD_A(0, mm);
#pragma unroll
    for (int nn = 0; nn < 4; ++nn) bfI[0][nn] = RD_B(0, nn);

    for (int kt = 0; kt < 60; kt += 4) {
        TILE(kt + 0, 0, 0, 1, 4, 1);
        TILE(kt + 1, 1, 1, 1, 4, 1);
        TILE(kt + 2, 2, 0, 1, 4, 1);
        TILE(kt + 3, 3, 1, 1, 4, 1);
    }
    TILE(60, 0, 0, 1, 4, 1);   // stages T63; drains T62
    TILE(61, 1, 1, 0, 0, 1);   // drains T63 before barrier
    TILE(62, 2, 0, 0, 0, 1);
    TILE(63, 3, 1, 0, 0, 0);

    // Epilogue (R3-validated): 16x16 C/D: col = lane&15, row = (lane>>4)*4 + reg
    const int r4 = (lane >> 4) * 4;
    const int cc = lane & 15;
#pragma unroll
    for (int m = 0; m < 4; ++m) {
        const int grow0 = brow + wm + m * 16 + r4;
        const float s0 = sL[grow0 + 0];
        const float s1 = sL[grow0 + 1];
        const float s2 = sL[grow0 + 2];
        const float s3 = sL[grow0 + 3];
#pragma unroll
        for (int n = 0; n < 8; ++n) {
            const int gcol = bcol + wn + n * 16 + cc;
            const float sc = sR[gcol];
            float* o = out + (size_t)grow0 * N_DIM + gcol;
            o[0 * N_DIM] = (float)acc[m][n][0] * s0 * sc;
            o[1 * N_DIM] = (float)acc[m][n][1] * s1 * sc;
            o[2 * N_DIM] = (float)acc[m][n][2] * s2 * sc;
            o[3 * N_DIM] = (float)acc[m][n][3] * s3 * sc;
        }
    }
}

// ---------------- launch ----------------
extern "C" void kernel_launch(void* const* d_in, const int* in_sizes, int n_in,
                              void* d_out, int out_size, void* d_ws, size_t ws_size,
                              hipStream_t stream) {
    const float* lhs = (const float*)d_in[0];
    const float* rhs = (const float*)d_in[1];
    float* out = (float*)d_out;

    uint8_t* ws = (uint8_t*)d_ws;
    int8_t* ql    = (int8_t*)ws;                               // 33,554,432 B
    int8_t* qbT   = (int8_t*)(ws + 33554432);                  // 16,777,216 B
    float* sL     = (float*)(ws + 50331648);                   // 32,768 B
    float* sR     = (float*)(ws + 50331648 + 32768);           // 16,384 B
    unsigned* bits = (unsigned*)(ws + 50331648 + 32768 + 16384); // 16,384 B

    hipMemsetAsync(bits, 0, N_DIM * sizeof(unsigned), stream);

    row_quant_kernel<<<M_DIM, 256, 0, stream>>>(lhs, sL, ql);
    col_absmax_kernel<<<dim3(N_DIM / 256, K_DIM / 64), 256, 0, stream>>>(rhs, bits);
    col_scale_kernel<<<N_DIM / 256, 256, 0, stream>>>(bits, sR);
    quant_rhs_t_kernel<<<dim3(N_DIM / 64, K_DIM / 64), 256, 0, stream>>>(rhs, sR, qbT);
    gemm_i8_kernel<<<dim3(M_DIM / 256 * N_DIM / 256), 512, 0, stream>>>(ql, qbT, sL, sR, out);
}